// Round 3
// baseline (9.865 us; speedup 1.0000x reference)
//
#include <hip/hip_runtime.h>
#include <math.h>

#define NP3 19200
#define NP4 4800
#define NP5 1200
#define NA  (NP3 + NP4 + NP5)   // 25200
#define MGT 64

// SCALE_CLAMP = log(224/8) = log(28)
#define SCALE_CLAMP_F 3.3322045101752038f
#define NEG_BIG (-100000000.0f)

// half_w, half_h per (level, aspect_ratio); host-side double math rounded to f32.
__constant__ float c_half[3][3][2] = {
    {{22.62741699796952f, 11.313708498984761f},
     {16.0f, 16.0f},
     {11.313708498984761f, 22.62741699796952f}},
    {{45.25483399593904f, 22.62741699796952f},
     {32.0f, 32.0f},
     {22.62741699796952f, 45.25483399593904f}},
    {{90.50966799187808f, 45.25483399593904f},
     {64.0f, 64.0f},
     {45.25483399593904f, 90.50966799187808f}},
};

// 8 lanes per anchor; each lane scans 8 GTs. Argmax via exact f64 cross-mul of
// f32 (inter, uni): products of f32 are exact in f64, so comparisons follow the
// TRUE ratios; rounding monotonicity => winner's rounded f32 IoU == reference's
// rounded max, and the single final f32 division reproduces quality bit-exactly.
// Tie-break at every level prefers the smaller GT index (jnp.argmax semantics).
__global__ __launch_bounds__(256)
void rpn_fused_kernel(const float* __restrict__ loc3,
                      const float* __restrict__ loc4,
                      const float* __restrict__ loc5,
                      const float* __restrict__ del3,
                      const float* __restrict__ del4,
                      const float* __restrict__ del5,
                      const float* __restrict__ gt,     // 64 x 5
                      float* __restrict__ out)
{
    __shared__ float4 sbox[MGT];           // x0,y0,x1,y1 per GT
    __shared__ float  sa2[MGT];            // |(x0-x1)*(y0-y1)|
    __shared__ float  scls[MGT];
    const int t = threadIdx.x;
    if (t < MGT) {
        const float g0 = gt[t * 5 + 0];
        const float g1 = gt[t * 5 + 1];
        const float g2 = gt[t * 5 + 2];
        const float g3 = gt[t * 5 + 3];
        sbox[t] = make_float4(g0, g1, g2, g3);
        sa2[t]  = fabsf((g0 - g2) * (g1 - g3));
        scls[t] = gt[t * 5 + 4];
    }
    __syncthreads();

    const int sub = t & 7;
    const int a = blockIdx.x * 32 + (t >> 3);
    if (a >= NA) return;

    // ---- level decode ----
    int lvl, rel;
    const float* locs;
    const float* dels;
    if (a < NP3)              { lvl = 0; rel = a;              locs = loc3; dels = del3; }
    else if (a < NP3 + NP4)   { lvl = 1; rel = a - NP3;        locs = loc4; dels = del4; }
    else                      { lvl = 2; rel = a - NP3 - NP4;  locs = loc5; dels = del5; }

    const int li = rel / 3;
    const int ar = rel - li * 3;

    // issue the delta load early (only the lane that needs it) to hide latency
    float4 del;
    if (sub == 0) del = *reinterpret_cast<const float4*>(dels + (size_t)rel * 4);

    // ---- anchor ----
    const float lx = locs[li * 2 + 0];
    const float ly = locs[li * 2 + 1];
    const float hw = c_half[lvl][ar][0];
    const float hh = c_half[lvl][ar][1];
    const float x0 = lx - hw, y0 = ly - hh;
    const float x1 = lx + hw, y1 = ly + hh;

    const float px = (x0 + x1) * 0.5f;
    const float py = (y0 + y1) * 0.5f;
    const float pw = fabsf(x0 - x1);
    const float ph = fabsf(y0 - y1);
    const float area1 = fabsf((x0 - x1) * (y0 - y1));

    // ---- 8 independent IoU numerator/denominator pairs (pipelines freely) ----
    const int j0 = sub * 8;
    float vi[8], vu[8];
    int   vj[8];
    #pragma unroll
    for (int i = 0; i < 8; ++i) {
        const int j = j0 + i;
        const float4 b = sbox[j];
        const float xl = fmaxf(x0, b.x);
        const float yb = fmaxf(y0, b.y);
        const float xr = fminf(x1, b.z);
        const float yt = fminf(y1, b.w);
        float inter = fabsf((xl - xr) * (yb - yt));
        if ((xl > xr) || (yb > yt)) inter = 0.0f;
        vi[i] = inter;
        vu[i] = (area1 + sa2[j]) - inter;   // ref f32 association order
        vj[i] = j;
    }

    // ---- in-lane tree argmax (3 levels; left = smaller j wins exact ties) ----
    #pragma unroll
    for (int s = 1; s < 8; s <<= 1) {
        #pragma unroll
        for (int k = 0; k < 8; k += 2 * s) {
            const double cl = (double)vi[k]     * (double)vu[k + s];
            const double cr = (double)vi[k + s] * (double)vu[k];
            if (cr > cl) { vi[k] = vi[k + s]; vu[k] = vu[k + s]; vj[k] = vj[k + s]; }
        }
    }
    float bi = vi[0], bu = vu[0];
    int   bj = vj[0];

    // ---- merge across the 8 sub-lanes (smaller index wins exact ties) ----
    #pragma unroll
    for (int m = 1; m <= 4; m <<= 1) {
        const float obi = __shfl_xor(bi, m, 64);
        const float obu = __shfl_xor(bu, m, 64);
        const int   obj = __shfl_xor(bj, m, 64);
        const double c1 = (double)bi  * (double)obu;
        const double c2 = (double)obi * (double)bu;
        if (c2 > c1 || (c2 == c1 && obj < bj)) { bi = obi; bu = obu; bj = obj; }
    }

    // ---- quality + classification (double thresholds, matching Python floats) ----
    const float q = bi / bu;     // one exact IEEE f32 division
    const float4 mb = sbox[bj];
    float m0 = mb.x, m1 = mb.y, m2 = mb.z, m3 = mb.w, m4 = scls[bj];
    const double qd = (double)q;
    if (qd <= 0.3) {
        m0 = m1 = m2 = m3 = m4 = -1.0f;
    } else if (qd < 0.7) {
        m0 = m1 = m2 = m3 = m4 = NEG_BIG;
    }

    // ---- outputs, split across sub-lanes ----
    if (sub == 0) {
        const float tx = del.x;
        const float ty = del.y;
        const float tw = fminf(del.z, SCALE_CLAMP_F);
        const float th = fminf(del.w, SCALE_CLAMP_F);
        const float bx = px + pw * tx;
        const float by = py + ph * ty;
        const float bw = pw * expf(tw);
        const float bh = ph * expf(th);
        float4 prop;
        prop.x = bx - bw * 0.5f;
        prop.y = by - bh * 0.5f;
        prop.z = bx + bw * 0.5f;
        prop.w = by + bw * 0.5f;   // reference uses bw here (ref bug, replicated)
        *reinterpret_cast<float4*>(out + (size_t)a * 4) = prop;
    } else if (sub == 1) {
        float* mout = out + (size_t)NA * 4 + (size_t)a * 5;
        mout[0] = m0; mout[1] = m1; mout[2] = m2; mout[3] = m3; mout[4] = m4;
    } else if (sub == 2) {
        float4 gd;
        if (m4 < 0.0f) {
            gd.x = gd.y = gd.z = gd.w = NEG_BIG;
        } else {
            const float bx = (m0 + m2) * 0.5f;
            const float by = (m1 + m3) * 0.5f;
            const float bw = fabsf(m0 - m2);
            const float bh = fabsf(m1 - m3);
            gd.x = (bx - px) / pw;
            gd.y = (by - py) / ph;
            gd.z = logf(fmaxf(bw, 1e-12f) / pw);
            gd.w = logf(fmaxf(bh, 1e-12f) / ph);
        }
        *reinterpret_cast<float4*>(out + (size_t)NA * 9 + (size_t)a * 4) = gd;
    }
}

extern "C" void kernel_launch(void* const* d_in, const int* in_sizes, int n_in,
                              void* d_out, int out_size, void* d_ws, size_t ws_size,
                              hipStream_t stream) {
    const float* loc3 = (const float*)d_in[0];
    const float* loc4 = (const float*)d_in[1];
    const float* loc5 = (const float*)d_in[2];
    const float* del3 = (const float*)d_in[3];
    const float* del4 = (const float*)d_in[4];
    const float* del5 = (const float*)d_in[5];
    const float* gt   = (const float*)d_in[6];
    float* out = (float*)d_out;

    const int grid = (NA + 31) / 32;   // 788 blocks, 32 anchors each, 8 lanes/anchor
    rpn_fused_kernel<<<grid, 256, 0, stream>>>(loc3, loc4, loc5,
                                               del3, del4, del5, gt, out);
}